// Round 6
// baseline (140.165 us; speedup 1.0000x reference)
//
#include <hip/hip_runtime.h>

#define NN 4096
#define LOG2E 1.44269504088896340736f
#define EXP2(x) __builtin_amdgcn_exp2f(x)

typedef float f32x4 __attribute__((ext_vector_type(4)));

// ---------------------------------------------------------------------------
// Kernel A: per-row stats. Grid (NN/64, nb), block 256. Block stages the full
// 4096-score row (16 KB), 4 threads per row each sum a k-quarter of
// |s_i - s_k|, LDS-merge, emit u = -s*log2e, vl = B*log2e.
__global__ __launch_bounds__(256) void k_rows(const float* __restrict__ scores,
                                              float* __restrict__ u,
                                              float* __restrict__ vl, int nb) {
    __shared__ float sch[NN];
    __shared__ float part[4][64];
    const int b = blockIdx.y, t = threadIdx.x;
    const float* srow = scores + (size_t)b * NN;
    for (int q = t * 4; q < NN; q += 1024)
        *reinterpret_cast<float4*>(&sch[q]) =
            *reinterpret_cast<const float4*>(&srow[q]);
    __syncthreads();
    const int r = t & 63;                  // row within block
    const int q = t >> 6;                  // k-quarter (uniform per wave)
    const float si = sch[blockIdx.x * 64 + r];
    float a0=0.f,a1=0.f,a2=0.f,a3=0.f,a4=0.f,a5=0.f,a6=0.f,a7=0.f;
    const int k0 = q * (NN / 4);
    for (int k = k0; k < k0 + NN / 4; k += 8) {
        float4 x = *reinterpret_cast<const float4*>(&sch[k]);
        float4 y = *reinterpret_cast<const float4*>(&sch[k + 4]);
        a0 += fabsf(si - x.x); a1 += fabsf(si - x.y);
        a2 += fabsf(si - x.z); a3 += fabsf(si - x.w);
        a4 += fabsf(si - y.x); a5 += fabsf(si - y.y);
        a6 += fabsf(si - y.z); a7 += fabsf(si - y.w);
    }
    part[q][r] = ((a0 + a1) + (a2 + a3)) + ((a4 + a5) + (a6 + a7));
    __syncthreads();
    if (t < 64) {
        const int ii = blockIdx.x * 64 + t;
        const float B = (part[0][t] + part[1][t]) + (part[2][t] + part[3][t]);
        u[(size_t)b * NN + ii]  = -sch[ii] * LOG2E;
        vl[(size_t)b * NN + ii] = B * LOG2E;
    }
}

// ---------------------------------------------------------------------------
// Kernel B: per-column softmax constant. Grid (NN/32, nb), block 256.
// Stage u and -v in LDS (32 KB); 8 threads per column, two passes (max,
// sum-of-exp2) with LDS merges. Emits w[b,j] = -m_j - log2(Z_j).
__global__ __launch_bounds__(256) void k_cols(const float* __restrict__ u,
                                              const float* __restrict__ vl,
                                              float* __restrict__ w, int nb) {
    __shared__ float su[NN];
    __shared__ float sv[NN];
    __shared__ float pm[8][32];
    __shared__ float pz[8][32];
    __shared__ float fm[32];
    const int b = blockIdx.y, t = threadIdx.x;
    const size_t base = (size_t)b * NN;
    for (int q4 = t * 4; q4 < NN; q4 += 1024) {
        float4 uu = *reinterpret_cast<const float4*>(&u[base + q4]);
        float4 vv = *reinterpret_cast<const float4*>(&vl[base + q4]);
        *reinterpret_cast<float4*>(&su[q4]) = uu;
        sv[q4] = -vv.x; sv[q4+1] = -vv.y; sv[q4+2] = -vv.z; sv[q4+3] = -vv.w;
    }
    __syncthreads();
    const int c = t & 31, q = t >> 5;
    const int j = blockIdx.x * 32 + c;
    const float cj = (float)(NN - 1 - 2 * j);
    const float4* su4 = reinterpret_cast<const float4*>(su);
    const float4* sv4 = reinterpret_cast<const float4*>(sv);
    const int i40 = q * (NN / 8) / 4, i41 = i40 + (NN / 8) / 4;
    float m0 = -3.4e38f, m1 = -3.4e38f;
    for (int i4 = i40; i4 < i41; ++i4) {
        float4 uu = su4[i4], vv = sv4[i4];
        m0 = fmaxf(m0, fmaf(uu.x, cj, vv.x));
        m1 = fmaxf(m1, fmaf(uu.y, cj, vv.y));
        m0 = fmaxf(m0, fmaf(uu.z, cj, vv.z));
        m1 = fmaxf(m1, fmaf(uu.w, cj, vv.w));
    }
    pm[q][c] = fmaxf(m0, m1);
    __syncthreads();
    if (t < 32) {
        float m = pm[0][t];
#pragma unroll
        for (int k = 1; k < 8; k++) m = fmaxf(m, pm[k][t]);
        fm[t] = m;
    }
    __syncthreads();
    const float m = fm[c];
    float z0 = 0.f, z1 = 0.f;
    for (int i4 = i40; i4 < i41; ++i4) {
        float4 uu = su4[i4], vv = sv4[i4];
        z0 += EXP2(fmaf(uu.x, cj, vv.x) - m);
        z1 += EXP2(fmaf(uu.y, cj, vv.y) - m);
        z0 += EXP2(fmaf(uu.z, cj, vv.z) - m);
        z1 += EXP2(fmaf(uu.w, cj, vv.w) - m);
    }
    pz[q][c] = z0 + z1;
    __syncthreads();
    if (t < 32) {
        float z = 0.f;
#pragma unroll
        for (int k = 0; k < 8; k++) z += pz[k][t];
        w[base + blockIdx.x * 32 + t] = -fm[t] - log2f(z);
    }
}

// ---------------------------------------------------------------------------
// Kernel C: out[b,i,j] = exp2(fma(u_i, c_j, w_j - v_i)).
// Grid (NN/2048, NN/32, nb), block 256; thread owns 8 consecutive columns
// (2 nontemporal dwordx4 stores/row), loops 32 rows. NT stores bypass the
// L3 allocate->dirty-evict churn (out buffer == L3 capacity, 256 MiB).
__global__ __launch_bounds__(256) void k_out(const float* __restrict__ u,
                                             const float* __restrict__ vl,
                                             const float* __restrict__ w,
                                             float* __restrict__ out, int nb) {
    __shared__ float su[32], sv[32];
    const int b = blockIdx.z, jc = blockIdx.x, t = threadIdx.x;
    const int i0 = blockIdx.y * 32;
    if (t < 32) {
        su[t] = u[(size_t)b * NN + i0 + t];
        sv[t] = vl[(size_t)b * NN + i0 + t];
    }
    const int j = jc * 2048 + t * 8;
    const float4 wa = *reinterpret_cast<const float4*>(w + (size_t)b * NN + j);
    const float4 wb = *reinterpret_cast<const float4*>(w + (size_t)b * NN + j + 4);
    const float c0 = (float)(NN - 1 - 2 * j);
    const float c1 = c0 - 2.f,  c2 = c0 - 4.f,  c3 = c0 - 6.f;
    const float c4 = c0 - 8.f,  c5 = c0 - 10.f, c6 = c0 - 12.f, c7 = c0 - 14.f;
    __syncthreads();
    float* orow = out + ((size_t)b * NN + i0) * NN + j;
#pragma unroll 4
    for (int r = 0; r < 32; r++) {
        const float ui = su[r], vi = sv[r];
        f32x4 oa, ob;
        oa.x = EXP2(fmaf(ui, c0, wa.x - vi));
        oa.y = EXP2(fmaf(ui, c1, wa.y - vi));
        oa.z = EXP2(fmaf(ui, c2, wa.z - vi));
        oa.w = EXP2(fmaf(ui, c3, wa.w - vi));
        ob.x = EXP2(fmaf(ui, c4, wb.x - vi));
        ob.y = EXP2(fmaf(ui, c5, wb.y - vi));
        ob.z = EXP2(fmaf(ui, c6, wb.z - vi));
        ob.w = EXP2(fmaf(ui, c7, wb.w - vi));
        float* p = orow + (size_t)r * NN;
        __builtin_nontemporal_store(oa, reinterpret_cast<f32x4*>(p));
        __builtin_nontemporal_store(ob, reinterpret_cast<f32x4*>(p + 4));
    }
}

// ---------------------------------------------------------------------------
extern "C" void kernel_launch(void* const* d_in, const int* in_sizes, int n_in,
                              void* d_out, int out_size, void* d_ws, size_t ws_size,
                              hipStream_t stream) {
    const float* scores = (const float*)d_in[0];
    float* out = (float*)d_out;
    const int nb = in_sizes[0] / NN;          // 4 batches
    const size_t S = (size_t)nb * NN;

    float* ws = (float*)d_ws;                 // 3*S floats = 192 KiB
    float* u  = ws;
    float* vl = u + S;
    float* w  = vl + S;

    hipLaunchKernelGGL(k_rows, dim3(NN / 64, nb), dim3(256), 0, stream,
                       scores, u, vl, nb);
    hipLaunchKernelGGL(k_cols, dim3(NN / 32, nb), dim3(256), 0, stream,
                       u, vl, w, nb);
    hipLaunchKernelGGL(k_out, dim3(NN / 2048, NN / 32, nb), dim3(256), 0, stream,
                       u, vl, w, out, nb);
}

// Round 7
// 67.768 us; speedup vs baseline: 2.0683x; 2.0683x over previous
//
#include <hip/hip_runtime.h>

#define NN 4096
#define LOG2E 1.44269504088896340736f
#define EXP2(x) __builtin_amdgcn_exp2f(x)

// ---------------------------------------------------------------------------
// Kernel A: per-row stats. Grid (NN/64, nb), block 256. Block stages the full
// 4096-score row (16 KB), 4 threads per row each sum a k-quarter of
// |s_i - s_k|, LDS-merge, emit u = -s*log2e, vl = B*log2e.
__global__ __launch_bounds__(256) void k_rows(const float* __restrict__ scores,
                                              float* __restrict__ u,
                                              float* __restrict__ vl, int nb) {
    __shared__ float sch[NN];
    __shared__ float part[4][64];
    const int b = blockIdx.y, t = threadIdx.x;
    const float* srow = scores + (size_t)b * NN;
    for (int q = t * 4; q < NN; q += 1024)
        *reinterpret_cast<float4*>(&sch[q]) =
            *reinterpret_cast<const float4*>(&srow[q]);
    __syncthreads();
    const int r = t & 63;                  // row within block
    const int q = t >> 6;                  // k-quarter (uniform per wave)
    const float si = sch[blockIdx.x * 64 + r];
    float a0=0.f,a1=0.f,a2=0.f,a3=0.f,a4=0.f,a5=0.f,a6=0.f,a7=0.f;
    const int k0 = q * (NN / 4);
    for (int k = k0; k < k0 + NN / 4; k += 8) {
        float4 x = *reinterpret_cast<const float4*>(&sch[k]);
        float4 y = *reinterpret_cast<const float4*>(&sch[k + 4]);
        a0 += fabsf(si - x.x); a1 += fabsf(si - x.y);
        a2 += fabsf(si - x.z); a3 += fabsf(si - x.w);
        a4 += fabsf(si - y.x); a5 += fabsf(si - y.y);
        a6 += fabsf(si - y.z); a7 += fabsf(si - y.w);
    }
    part[q][r] = ((a0 + a1) + (a2 + a3)) + ((a4 + a5) + (a6 + a7));
    __syncthreads();
    if (t < 64) {
        const int ii = blockIdx.x * 64 + t;
        const float B = (part[0][t] + part[1][t]) + (part[2][t] + part[3][t]);
        u[(size_t)b * NN + ii]  = -sch[ii] * LOG2E;
        vl[(size_t)b * NN + ii] = B * LOG2E;
    }
}

// ---------------------------------------------------------------------------
// Kernel B: per-column softmax constant. Grid (NN/32, nb), block 256.
// Stage u and -v in LDS (32 KB); 8 threads per column, two passes (max,
// sum-of-exp2) with LDS merges. Emits w[b,j] = -m_j - log2(Z_j).
__global__ __launch_bounds__(256) void k_cols(const float* __restrict__ u,
                                              const float* __restrict__ vl,
                                              float* __restrict__ w, int nb) {
    __shared__ float su[NN];
    __shared__ float sv[NN];
    __shared__ float pm[8][32];
    __shared__ float pz[8][32];
    __shared__ float fm[32];
    const int b = blockIdx.y, t = threadIdx.x;
    const size_t base = (size_t)b * NN;
    for (int q4 = t * 4; q4 < NN; q4 += 1024) {
        float4 uu = *reinterpret_cast<const float4*>(&u[base + q4]);
        float4 vv = *reinterpret_cast<const float4*>(&vl[base + q4]);
        *reinterpret_cast<float4*>(&su[q4]) = uu;
        sv[q4] = -vv.x; sv[q4+1] = -vv.y; sv[q4+2] = -vv.z; sv[q4+3] = -vv.w;
    }
    __syncthreads();
    const int c = t & 31, q = t >> 5;
    const int j = blockIdx.x * 32 + c;
    const float cj = (float)(NN - 1 - 2 * j);
    const float4* su4 = reinterpret_cast<const float4*>(su);
    const float4* sv4 = reinterpret_cast<const float4*>(sv);
    const int i40 = q * (NN / 8) / 4, i41 = i40 + (NN / 8) / 4;
    float m0 = -3.4e38f, m1 = -3.4e38f;
    for (int i4 = i40; i4 < i41; ++i4) {
        float4 uu = su4[i4], vv = sv4[i4];
        m0 = fmaxf(m0, fmaf(uu.x, cj, vv.x));
        m1 = fmaxf(m1, fmaf(uu.y, cj, vv.y));
        m0 = fmaxf(m0, fmaf(uu.z, cj, vv.z));
        m1 = fmaxf(m1, fmaf(uu.w, cj, vv.w));
    }
    pm[q][c] = fmaxf(m0, m1);
    __syncthreads();
    if (t < 32) {
        float m = pm[0][t];
#pragma unroll
        for (int k = 1; k < 8; k++) m = fmaxf(m, pm[k][t]);
        fm[t] = m;
    }
    __syncthreads();
    const float m = fm[c];
    float z0 = 0.f, z1 = 0.f;
    for (int i4 = i40; i4 < i41; ++i4) {
        float4 uu = su4[i4], vv = sv4[i4];
        z0 += EXP2(fmaf(uu.x, cj, vv.x) - m);
        z1 += EXP2(fmaf(uu.y, cj, vv.y) - m);
        z0 += EXP2(fmaf(uu.z, cj, vv.z) - m);
        z1 += EXP2(fmaf(uu.w, cj, vv.w) - m);
    }
    pz[q][c] = z0 + z1;
    __syncthreads();
    if (t < 32) {
        float z = 0.f;
#pragma unroll
        for (int k = 0; k < 8; k++) z += pz[k][t];
        w[base + blockIdx.x * 32 + t] = -fm[t] - log2f(z);
    }
}

// ---------------------------------------------------------------------------
// Kernel C: out[b,i,j] = exp2(fma(u_i, c_j, w_j - v_i)).
// Grid (NN/1024, NN/32, nb), block 256; thread owns 4 consecutive columns
// (one contiguous float4 store per row — full wave coalescing, as R4).
// Geometric chain cuts exp2 count 4x: out[i,j+1] = out[i,j]*g_i*d_{j+1},
// g_i = exp2(-2u_i) (per-row, from LDS), d = exp2(w_{j+1}-w_j) (per-thread
// constant). Delta-of-floats is exact to ulp(delta); the stored-w rounding
// cancels since y0 uses the same w values -> no accuracy loss.
__global__ __launch_bounds__(256) void k_out(const float* __restrict__ u,
                                             const float* __restrict__ vl,
                                             const float* __restrict__ w,
                                             float* __restrict__ out, int nb) {
    __shared__ float su[32], sv[32], sg[32];
    const int b = blockIdx.z, jc = blockIdx.x, t = threadIdx.x;
    const int i0 = blockIdx.y * 32;
    if (t < 32) {
        const float uu = u[(size_t)b * NN + i0 + t];
        su[t] = uu;
        sv[t] = vl[(size_t)b * NN + i0 + t];
        sg[t] = EXP2(-2.0f * uu);
    }
    const int j = jc * 1024 + t * 4;
    const float4 w4 = *reinterpret_cast<const float4*>(w + (size_t)b * NN + j);
    const float d1 = EXP2(w4.y - w4.x);
    const float d2 = EXP2(w4.z - w4.y);
    const float d3 = EXP2(w4.w - w4.z);
    const float c0 = (float)(NN - 1 - 2 * j);
    __syncthreads();
    float* orow = out + ((size_t)b * NN + i0) * NN + j;
#pragma unroll 4
    for (int r = 0; r < 32; r++) {
        const float ui = su[r], vi = sv[r], gi = sg[r];
        float4 o;
        o.x = EXP2(fmaf(ui, c0, w4.x - vi));
        o.y = o.x * (gi * d1);
        o.z = o.y * (gi * d2);
        o.w = o.z * (gi * d3);
        *reinterpret_cast<float4*>(orow + (size_t)r * NN) = o;
    }
}

// ---------------------------------------------------------------------------
extern "C" void kernel_launch(void* const* d_in, const int* in_sizes, int n_in,
                              void* d_out, int out_size, void* d_ws, size_t ws_size,
                              hipStream_t stream) {
    const float* scores = (const float*)d_in[0];
    float* out = (float*)d_out;
    const int nb = in_sizes[0] / NN;          // 4 batches
    const size_t S = (size_t)nb * NN;

    float* ws = (float*)d_ws;                 // 3*S floats = 192 KiB
    float* u  = ws;
    float* vl = u + S;
    float* w  = vl + S;

    hipLaunchKernelGGL(k_rows, dim3(NN / 64, nb), dim3(256), 0, stream,
                       scores, u, vl, nb);
    hipLaunchKernelGGL(k_cols, dim3(NN / 32, nb), dim3(256), 0, stream,
                       u, vl, w, nb);
    hipLaunchKernelGGL(k_out, dim3(NN / 1024, NN / 32, nb), dim3(256), 0, stream,
                       u, vl, w, out, nb);
}